// Round 1
// baseline (19.490 us; speedup 1.0000x reference)
//
#include <hip/hip_runtime.h>
#include <hip/hip_bf16.h>

// LengthRegulator: dur (32,4096) int32 in [0,16) -> mel2ph (32,T_mel) int32.
// cs = cumsum(dur, axis=1); mel2ph[b,p] = (p < cs[b,4095]) ? upper_bound(cs[b], p)+1 : 0
// T_mel = out_size / n_rows (fixed by harness from the reference's data-dependent shape).

#define COLS 4096
#define SCAN_THREADS 256
#define ITEMS_PER_THREAD 16  // 256*16 = 4096

__global__ void lr_cumsum_kernel(const int* __restrict__ dur, int* __restrict__ cs) {
    __shared__ int sums[SCAN_THREADS];
    const int row = blockIdx.x;
    const int t = threadIdx.x;
    const int* __restrict__ drow = dur + (size_t)row * COLS;
    int* __restrict__ crow = cs + (size_t)row * COLS;

    // Load 16 consecutive ints as 4x int4
    int v[ITEMS_PER_THREAD];
    const int4* d4 = reinterpret_cast<const int4*>(drow) + t * 4;
#pragma unroll
    for (int i = 0; i < 4; ++i) {
        int4 a = d4[i];
        v[i * 4 + 0] = a.x;
        v[i * 4 + 1] = a.y;
        v[i * 4 + 2] = a.z;
        v[i * 4 + 3] = a.w;
    }
    // local inclusive prefix
#pragma unroll
    for (int i = 1; i < ITEMS_PER_THREAD; ++i) v[i] += v[i - 1];

    sums[t] = v[ITEMS_PER_THREAD - 1];
    __syncthreads();
    // Hillis-Steele inclusive scan over 256 thread sums
#pragma unroll
    for (int off = 1; off < SCAN_THREADS; off <<= 1) {
        int add = (t >= off) ? sums[t - off] : 0;
        __syncthreads();
        sums[t] += add;
        __syncthreads();
    }
    int excl = (t == 0) ? 0 : sums[t - 1];

    // write cumsum (vectorized)
    int4* c4 = reinterpret_cast<int4*>(crow) + t * 4;
#pragma unroll
    for (int i = 0; i < 4; ++i) {
        int4 a;
        a.x = v[i * 4 + 0] + excl;
        a.y = v[i * 4 + 1] + excl;
        a.z = v[i * 4 + 2] + excl;
        a.w = v[i * 4 + 3] + excl;
        c4[i] = a;
    }
}

__global__ void lr_fill_kernel(const int* __restrict__ cs, int* __restrict__ out, int T_mel) {
    const int row = blockIdx.y;
    const int p = blockIdx.x * blockDim.x + threadIdx.x;
    if (p >= T_mel) return;
    const int* __restrict__ crow = cs + (size_t)row * COLS;
    const int total = crow[COLS - 1];
    int val = 0;
    if (p < total) {
        // upper_bound: first idx with crow[idx] > p  (== # elems <= p)
        int lo = 0, hi = COLS;
        while (lo < hi) {
            int mid = (lo + hi) >> 1;
            if (crow[mid] <= p) lo = mid + 1; else hi = mid;
        }
        val = lo + 1;
    }
    out[(size_t)row * T_mel + p] = val;
}

extern "C" void kernel_launch(void* const* d_in, const int* in_sizes, int n_in,
                              void* d_out, int out_size, void* d_ws, size_t ws_size,
                              hipStream_t stream) {
    const int* dur = (const int*)d_in[0];
    int* out = (int*)d_out;
    int* cs = (int*)d_ws;  // 32*4096*4 = 512 KB scratch

    const int rows = in_sizes[0] / COLS;   // 32
    const int T_mel = out_size / rows;

    lr_cumsum_kernel<<<rows, SCAN_THREADS, 0, stream>>>(dur, cs);

    dim3 grid((T_mel + 255) / 256, rows);
    lr_fill_kernel<<<grid, 256, 0, stream>>>(cs, out, T_mel);
}

// Round 2
// 16.568 us; speedup vs baseline: 1.1764x; 1.1764x over previous
//
#include <hip/hip_runtime.h>
#include <hip/hip_bf16.h>

// LengthRegulator fused single-kernel:
// cs = cumsum(dur[row]) computed per-block in LDS; each block fills a
// CHUNK-wide slice of out[row] via 12-step binary search in LDS.
// mel2ph[b,p] = (p < cs[4095]) ? upper_bound(cs, p)+1 : 0

#define COLS 4096
#define THREADS 256
#define CHUNK 4096          // output positions per block
#define ITEMS 16            // COLS / THREADS

__global__ __launch_bounds__(THREADS) void lr_fused_kernel(
    const int* __restrict__ dur, int* __restrict__ out, int T_mel) {
    __shared__ int cs[COLS];       // 16 KB: inclusive cumsum of the row
    __shared__ int sums[THREADS];

    const int row = blockIdx.y;
    const int t = threadIdx.x;

    // ---- Phase 1: row cumsum into LDS ----
    const int4* d4 = reinterpret_cast<const int4*>(dur + (size_t)row * COLS) + t * 4;
    int v[ITEMS];
#pragma unroll
    for (int i = 0; i < 4; ++i) {
        int4 a = d4[i];
        v[i * 4 + 0] = a.x;
        v[i * 4 + 1] = a.y;
        v[i * 4 + 2] = a.z;
        v[i * 4 + 3] = a.w;
    }
#pragma unroll
    for (int i = 1; i < ITEMS; ++i) v[i] += v[i - 1];

    sums[t] = v[ITEMS - 1];
    __syncthreads();
#pragma unroll
    for (int off = 1; off < THREADS; off <<= 1) {
        int add = (t >= off) ? sums[t - off] : 0;
        __syncthreads();
        sums[t] += add;
        __syncthreads();
    }
    const int excl = (t == 0) ? 0 : sums[t - 1];
#pragma unroll
    for (int i = 0; i < ITEMS; ++i) cs[t * ITEMS + i] = v[i] + excl;
    __syncthreads();

    // ---- Phase 2: fill this block's output chunk ----
    const int total = cs[COLS - 1];
    int* __restrict__ orow = out + (size_t)row * T_mel;
    const int chunk_base = blockIdx.x * CHUNK;

#pragma unroll
    for (int j = 0; j < CHUNK / THREADS; ++j) {
        const int p = chunk_base + j * THREADS + t;   // lanes contiguous -> coalesced store
        if (p >= T_mel) continue;
        int val = 0;
        if (p < total) {
            // upper_bound over cs[0..4095]: exactly 12 halving steps
            int lo = 0, hi = COLS;
#pragma unroll
            for (int s = 0; s < 12; ++s) {
                const int mid = (lo + hi) >> 1;
                const bool le = (cs[mid] <= p);
                lo = le ? mid + 1 : lo;
                hi = le ? hi : mid;
            }
            val = lo + 1;
        }
        orow[p] = val;
    }
}

extern "C" void kernel_launch(void* const* d_in, const int* in_sizes, int n_in,
                              void* d_out, int out_size, void* d_ws, size_t ws_size,
                              hipStream_t stream) {
    const int* dur = (const int*)d_in[0];
    int* out = (int*)d_out;

    const int rows = in_sizes[0] / COLS;   // 32
    const int T_mel = out_size / rows;

    dim3 grid((T_mel + CHUNK - 1) / CHUNK, rows);
    lr_fused_kernel<<<grid, THREADS, 0, stream>>>(dur, out, T_mel);
}

// Round 3
// 13.361 us; speedup vs baseline: 1.4588x; 1.2401x over previous
//
#include <hip/hip_runtime.h>
#include <hip/hip_bf16.h>

// LengthRegulator, scatter formulation:
// Each block owns (row, chunk of CHUNK output positions).
// Phase 1: row cumsum — per-thread local prefix (16 items in registers) +
//          wave shfl-scan + cross-wave LDS combine (1 barrier).
// Phase 2: zero LDS out-tile; each thread scatters tok+1 over its tokens'
//          clipped ranges [cs[tok-1], cs[tok]) ∩ chunk  (values all in regs).
// Phase 3: coalesced copy LDS tile -> global.
// mel2ph[b,p] = (p < total) ? (# cs entries <= p) + 1 : 0  — scatter is exact.

#define COLS 4096
#define THREADS 256
#define CHUNK 4096
#define ITEMS 16            // COLS / THREADS
#define NWAVES 4            // THREADS / 64

__global__ __launch_bounds__(THREADS) void lr_scatter_kernel(
    const int* __restrict__ dur, int* __restrict__ out, int T_mel) {
    __shared__ int out_lds[CHUNK];   // 16 KB output tile
    __shared__ int wsum[NWAVES];

    const int row = blockIdx.y;
    const int t = threadIdx.x;
    const int lane = t & 63;
    const int wid = t >> 6;
    const int base = blockIdx.x * CHUNK;

    // ---- load 16 durations into registers ----
    const int4* d4 = reinterpret_cast<const int4*>(dur + (size_t)row * COLS) + t * 4;
    int v[ITEMS];
#pragma unroll
    for (int i = 0; i < 4; ++i) {
        int4 a = d4[i];
        v[i * 4 + 0] = a.x;
        v[i * 4 + 1] = a.y;
        v[i * 4 + 2] = a.z;
        v[i * 4 + 3] = a.w;
    }

    // ---- zero the output tile (coalesced, conflict-free) ----
#pragma unroll
    for (int j = 0; j < CHUNK / THREADS; ++j) out_lds[j * THREADS + t] = 0;

    // ---- local inclusive prefix over 16 items ----
#pragma unroll
    for (int i = 1; i < ITEMS; ++i) v[i] += v[i - 1];
    const int mysum = v[ITEMS - 1];

    // ---- wave inclusive scan of thread sums (6 shfl steps, no barriers) ----
    int inc = mysum;
#pragma unroll
    for (int off = 1; off < 64; off <<= 1) {
        int n = __shfl_up(inc, off, 64);
        if (lane >= off) inc += n;
    }
    if (lane == 63) wsum[wid] = inc;
    __syncthreads();   // also guarantees out_lds zeroing is complete

    int wbase = 0;
#pragma unroll
    for (int w = 0; w < NWAVES; ++w) wbase += (w < wid) ? wsum[w] : 0;
    const int total = wsum[0] + wsum[1] + wsum[2] + wsum[3];
    const int excl = wbase + inc - mysum;   // exclusive prefix for this thread's first token

    // ---- scatter tok+1 over clipped ranges ----
    const int chunk_end = base + CHUNK;
    if (excl < chunk_end && excl + mysum > base) {   // thread's span intersects chunk
        int prev = excl;
#pragma unroll
        for (int i = 0; i < ITEMS; ++i) {
            const int cur = excl + v[i];
            const int s0 = prev > base ? prev : base;
            const int e0 = cur < chunk_end ? cur : chunk_end;
            const int val = t * ITEMS + i + 1;
            for (int q = s0; q < e0; ++q) out_lds[q - base] = val;
            prev = cur;
        }
    }
    __syncthreads();

    // ---- coalesced copy to global ----
    int* __restrict__ orow = out + (size_t)row * T_mel;
    const int limit0 = T_mel - base;
    const int limit = limit0 < CHUNK ? limit0 : CHUNK;
#pragma unroll
    for (int j = 0; j < CHUNK / THREADS; ++j) {
        const int idx = j * THREADS + t;
        if (idx < limit) orow[base + idx] = out_lds[idx];
    }
    (void)total;  // total implicitly handled: positions >= total stay 0
}

extern "C" void kernel_launch(void* const* d_in, const int* in_sizes, int n_in,
                              void* d_out, int out_size, void* d_ws, size_t ws_size,
                              hipStream_t stream) {
    const int* dur = (const int*)d_in[0];
    int* out = (int*)d_out;

    const int rows = in_sizes[0] / COLS;   // 32
    const int T_mel = out_size / rows;

    dim3 grid((T_mel + CHUNK - 1) / CHUNK, rows);
    lr_scatter_kernel<<<grid, THREADS, 0, stream>>>(dur, out, T_mel);
}